// Round 7
// baseline (197.857 us; speedup 1.0000x reference)
//
#include <hip/hip_runtime.h>
#include <hip/hip_bf16.h>

#define C_IN    64
#define C_OUT   128
#define HH      112
#define WW      112
#define NB      16
#define KTOT    576      // C_IN * 9
#define NSTEPS  36       // KTOT / 16
#define NPIX    (HH*WW)  // 12544
#define PH      114      // padded spatial dim
#define PPIX    (PH*PH)  // 12996
#define XT_OFF  147456   // bytes: pw occupies [0, 147456)
#define XT_BYTES ((size_t)NB * PPIX * C_IN * 2)
// A-reg tiling: block = 64 c_out x (16w x 8h) tile, 7 tiles per half-strip
#define HB_X    18
#define HB_P    180      // 10*18 halo pixels
#define BBUF    24576    // 6 rounds * 4096 B per B buffer (23040 used)
// fallback tiling (round-2 kernel)
#define TY      8
#define TX      16
#define HALO_X  18
#define HALO_P  180
#define TILES_X 7
#define NTILES  98

typedef __bf16 bf16x8 __attribute__((ext_vector_type(8)));
typedef float  f32x16 __attribute__((ext_vector_type(16)));

static __device__ __forceinline__ unsigned short f2bf(float v) {
    unsigned int u = __builtin_bit_cast(unsigned int, v);
    u = u + 0x7fffu + ((u >> 16) & 1u);   // RNE
    return (unsigned short)(u >> 16);
}

// ---------------- pack spW = weight*mask into bf16 MFMA A-fragments ----------------
// pw_frag[t][mt][lane] = 16 B (8 bf16); k_log(t,g,e)=t*16+g*8+e; ij=k_log>>6, c=k_log&63; k_orig=c*9+ij
__global__ __launch_bounds__(256) void pack_w_kernel(
        const float* __restrict__ weight, const float* __restrict__ mask,
        unsigned short* __restrict__ pw) {
    int t  = blockIdx.x;           // 0..35
    int mt = threadIdx.x >> 6;     // 0..3
    int l  = threadIdx.x & 63;
    int g  = l >> 5;
    int m  = mt * 32 + (l & 31);
    unsigned int words[4];
    #pragma unroll
    for (int ew = 0; ew < 4; ++ew) {
        unsigned int w2[2];
        #pragma unroll
        for (int h = 0; h < 2; ++h) {
            int e    = ew * 2 + h;
            int klog = t * 16 + g * 8 + e;
            int ij   = klog >> 6;
            int c    = klog & 63;
            int ko   = c * 9 + ij;
            w2[h] = f2bf(weight[m * KTOT + ko] * mask[m * KTOT + ko]);
        }
        words[ew] = w2[0] | (w2[1] << 16);
    }
    uint4 o4; o4.x = words[0]; o4.y = words[1]; o4.z = words[2]; o4.w = words[3];
    ((uint4*)pw)[(t * 4 + mt) * 64 + l] = o4;
}

// ---------------- pre-pass: x [b][c][h][w] fp32 -> xT [b][hp][wp][c] bf16, zero-padded ----------------
__global__ __launch_bounds__(256) void transpose_x_kernel(
        const float* __restrict__ x, unsigned short* __restrict__ xT) {
    const int b  = blockIdx.y;
    const int pp = blockIdx.x * 256 + threadIdx.x;
    if (pp >= PPIX) return;
    const int hp = pp / PH, wp = pp - hp * PH;
    const int gh = hp - 1, gw = wp - 1;
    const bool valid = (unsigned)gh < (unsigned)HH && (unsigned)gw < (unsigned)WW;
    const float* src = x + (size_t)b * C_IN * (HH * WW) + (gh * WW + gw);
    uint4* dst = (uint4*)(xT + ((size_t)b * PPIX + pp) * C_IN);
    #pragma unroll
    for (int cb = 0; cb < 8; ++cb) {
        unsigned int w4[4];
        #pragma unroll
        for (int h = 0; h < 4; ++h) {
            float v0 = valid ? src[(size_t)(cb * 8 + h * 2    ) * (HH * WW)] : 0.0f;
            float v1 = valid ? src[(size_t)(cb * 8 + h * 2 + 1) * (HH * WW)] : 0.0f;
            w4[h] = (unsigned)f2bf(v0) | ((unsigned)f2bf(v1) << 16);
        }
        uint4 o; o.x = w4[0]; o.y = w4[1]; o.z = w4[2]; o.w = w4[3];
        dst[cb] = o;
    }
}

// ---------------- main conv: A-in-registers, double-buffered B ----------------
// Block (256 thr, 4 waves) = M-half mh (64 c_out) x half-strip (16 wide, 7 tiles of 16x8).
// Wave (mt, nh): A for M-tile mt held in 36 uint4 regs; per iter stage 10x18 halo into
// Bs[buf] (dbuf, stage-ahead), then 36 fully-unrolled K-steps: 2 ds_read_b128 + 2 MFMA.
__global__ __launch_bounds__(256, 2) void sparse_conv_areg_kernel(
        const unsigned short* __restrict__ xT, const unsigned short* __restrict__ pw,
        const float* __restrict__ bias, float* __restrict__ out) {
    __shared__ __align__(16) unsigned char Bs[2][BBUF];   // 49152 B

    // XCD-bijective swizzle: 448 % 8 == 0; XCD k gets 56 contiguous bids (2 images)
    const int bid  = (blockIdx.x & 7) * 56 + (blockIdx.x >> 3);
    const int b    = bid / 28;
    const int rem  = bid % 28;
    const int mh   = rem & 1;
    const int half = (rem >> 1) & 1;
    const int strip= rem >> 2;          // 0..6
    const int w0   = strip * 16;
    const int tid  = threadIdx.x;
    const int wave = tid >> 6, l = tid & 63;
    const int mt = wave >> 1, nh = wave & 1;
    const int g  = l >> 5,  ln = l & 31;

    const char* xTb = (const char*)xT + (size_t)b * PPIX * (C_IN * 2);
    const uint4* __restrict__ pwv = (const uint4*)pw;

    // ---- A into registers: 36 x 16B (144 VGPR), one M-tile per wave ----
    uint4 Areg[NSTEPS];
    #pragma unroll
    for (int t = 0; t < NSTEPS; ++t)
        Areg[t] = pwv[(t * 4 + mh * 2 + mt) * 64 + l];

    // ---- bias by accumulator slot ----
    float bv[16];
    #pragma unroll
    for (int r = 0; r < 16; ++r) {
        int mloc = (r & 3) + 8 * (r >> 2) + 4 * g;
        bv[r] = bias[mh * 64 + mt * 32 + mloc];
    }

    // per-lane pixel bases for the 2 N-subtiles (tile = 16w x 8h)
    int Pbase[2];
    #pragma unroll
    for (int ntp = 0; ntp < 2; ++ntp) {
        int p = nh * 64 + ntp * 32 + ln;
        Pbase[ntp] = (p >> 4) * HB_X + (p & 15);
    }

    // ---- staging: 6 rounds of global_load_lds, linear dest, pre-swizzled source ----
    auto STAGE = [&](int it, int buf) {
        const int base = half * 56 + it * 8;   // padded top row of halo
        #pragma unroll
        for (int r = 0; r < 6; ++r) {
            int chunk = r * 256 + tid;
            if (chunk > HB_P * 8 - 1) chunk = HB_P * 8 - 1;   // dup tail, dest stays linear
            int p = chunk >> 3, s = chunk & 7;
            int yy = p / HB_X, xx = p - yy * HB_X;
            const char* gp = xTb + (size_t)((base + yy) * PH + (w0 + xx)) * (C_IN * 2)
                                 + (((s ^ p) & 7) << 4);
            char* lp = (char*)&Bs[buf][0] + r * 4096 + wave * 1024;   // + lane*16 by HW
            __builtin_amdgcn_global_load_lds(
                (const __attribute__((address_space(1))) void*)gp,
                (__attribute__((address_space(3))) void*)lp, 16, 0, 0);
        }
    };

    STAGE(0, 0);
    __syncthreads();

    const size_t outb = (size_t)b * C_OUT * NPIX;

    #pragma unroll 1
    for (int it = 0; it < 7; ++it) {
        const int cur = it & 1;
        if (it < 6) STAGE(it + 1, cur ^ 1);   // issue next-tile loads; complete during MFMA

        f32x16 acc[2];
        #pragma unroll
        for (int ntp = 0; ntp < 2; ++ntp)
            #pragma unroll
            for (int r = 0; r < 16; ++r) acc[ntp][r] = bv[r];

        const unsigned char* Bc = &Bs[cur][0];
        #pragma unroll
        for (int t = 0; t < NSTEPS; ++t) {
            const int ij = t >> 2, cs = t & 3;
            const int di = ij / 3, dj = ij - di * 3;
            const int jb = cs * 2 + g;
            bf16x8 a = __builtin_bit_cast(bf16x8, Areg[t]);
            #pragma unroll
            for (int ntp = 0; ntp < 2; ++ntp) {
                const int Pa = Pbase[ntp] + di * HB_X + dj;
                bf16x8 bb = __builtin_bit_cast(bf16x8,
                    *(const uint4*)(Bc + Pa * (C_IN * 2) + (((jb ^ Pa) & 7) << 4)));
                acc[ntp] = __builtin_amdgcn_mfma_f32_32x32x16_bf16(a, bb, acc[ntp], 0, 0, 0);
            }
        }

        // ---- store: C/D col=lane&31 (pixel), row=(r&3)+8*(r>>2)+4*g ----
        const int rowbase = half * 56 + it * 8;
        #pragma unroll
        for (int r = 0; r < 16; ++r) {
            int mloc = (r & 3) + 8 * (r >> 2) + 4 * g;
            int o = mh * 64 + mt * 32 + mloc;
            #pragma unroll
            for (int ntp = 0; ntp < 2; ++ntp) {
                int p = nh * 64 + ntp * 32 + ln;
                out[outb + (size_t)o * NPIX + (rowbase + (p >> 4)) * WW + w0 + (p & 15)]
                    = acc[ntp][r];
            }
        }
        __syncthreads();   // staged it+1 ready; all waves done with buf cur
    }
}

// ---------------- fallback (round-2 kernel) if ws too small for xT ----------------
__global__ __launch_bounds__(256, 4) void sparse_conv_fb_kernel(
        const float* __restrict__ x, const unsigned short* __restrict__ pw,
        const float* __restrict__ bias, float* __restrict__ out) {
    __shared__ __align__(16) unsigned short xs[HALO_P * C_IN];

    const int bid = blockIdx.x;
    const int b   = bid / NTILES;
    const int t98 = bid % NTILES;
    const int tyi = t98 / TILES_X;
    const int txi = t98 % TILES_X;
    const int h0  = tyi * TY, w0 = txi * TX;
    const int tid = threadIdx.x;

    const float* xb = x + (size_t)b * C_IN * HH * WW;
    {
        const int p  = tid;
        const bool act = p < HALO_P;
        int yy = p / HALO_X;
        int xx = p - yy * HALO_X;
        int gh = h0 + yy - 1, gw = w0 + xx - 1;
        const bool valid = act && (unsigned)gh < (unsigned)HH && (unsigned)gw < (unsigned)WW;
        const float* bp = xb + (gh * WW + gw);
        float v[C_IN];
        #pragma unroll
        for (int c = 0; c < C_IN; ++c)
            v[c] = valid ? bp[c * (HH * WW)] : 0.0f;
        if (act) {
            char* xc = (char*)xs + p * (C_IN * 2);
            #pragma unroll
            for (int j = 0; j < 8; ++j) {
                bf16x8 bvv;
                #pragma unroll
                for (int e = 0; e < 8; ++e) bvv[e] = (__bf16)v[j * 8 + e];
                *(uint4*)(xc + (((j ^ p) & 7) << 4)) = __builtin_bit_cast(uint4, bvv);
            }
        }
    }
    __syncthreads();

    const int wave = tid >> 6, l = tid & 63;
    const int wm = wave >> 1, wn = wave & 1;
    const int g  = l >> 5,  ln = l & 31;

    int P0[2];
    #pragma unroll
    for (int ntp = 0; ntp < 2; ++ntp) {
        int pt = wn * 64 + ntp * 32 + ln;
        P0[ntp] = (pt >> 4) * HALO_X + (pt & 15);
    }

    f32x16 acc[2][2];
    #pragma unroll
    for (int i = 0; i < 2; ++i)
        #pragma unroll
        for (int jq = 0; jq < 2; ++jq)
            #pragma unroll
            for (int q = 0; q < 16; ++q) acc[i][jq][q] = 0.0f;

    const uint4* __restrict__ pwv = (const uint4*)pw;

    #pragma unroll 1
    for (int ij = 0; ij < 9; ++ij) {
        const int di = ij / 3;
        const int dj = ij - di * 3;
        const int P0a = P0[0] + di * HALO_X + dj;
        const int P1a = P0[1] + di * HALO_X + dj;
        #pragma unroll
        for (int cs = 0; cs < 4; ++cs) {
            const int t = ij * 4 + cs;
            bf16x8 a0 = __builtin_bit_cast(bf16x8, pwv[(t * 4 + wm * 2 + 0) * 64 + l]);
            bf16x8 a1 = __builtin_bit_cast(bf16x8, pwv[(t * 4 + wm * 2 + 1) * 64 + l]);
            const int jb = cs * 2 + g;
            bf16x8 b0 = __builtin_bit_cast(bf16x8,
                *(const uint4*)((const char*)xs + P0a * (C_IN * 2) + (((jb ^ P0a) & 7) << 4)));
            bf16x8 b1 = __builtin_bit_cast(bf16x8,
                *(const uint4*)((const char*)xs + P1a * (C_IN * 2) + (((jb ^ P1a) & 7) << 4)));
            acc[0][0] = __builtin_amdgcn_mfma_f32_32x32x16_bf16(a0, b0, acc[0][0], 0, 0, 0);
            acc[0][1] = __builtin_amdgcn_mfma_f32_32x32x16_bf16(a0, b1, acc[0][1], 0, 0, 0);
            acc[1][0] = __builtin_amdgcn_mfma_f32_32x32x16_bf16(a1, b0, acc[1][0], 0, 0, 0);
            acc[1][1] = __builtin_amdgcn_mfma_f32_32x32x16_bf16(a1, b1, acc[1][1], 0, 0, 0);
        }
    }

    const size_t outb = (size_t)b * C_OUT * HH * WW;
    #pragma unroll
    for (int mtp = 0; mtp < 2; ++mtp) {
        #pragma unroll
        for (int r = 0; r < 16; ++r) {
            int mloc = (r & 3) + 8 * (r >> 2) + 4 * g;
            int o = (wm * 2 + mtp) * 32 + mloc;
            float bvv = bias[o];
            #pragma unroll
            for (int ntp = 0; ntp < 2; ++ntp) {
                int p  = wn * 64 + ntp * 32 + ln;
                int gh = h0 + (p >> 4), gw = w0 + (p & 15);
                out[outb + ((size_t)o * HH + gh) * WW + gw] = acc[mtp][ntp][r] + bvv;
            }
        }
    }
}

extern "C" void kernel_launch(void* const* d_in, const int* in_sizes, int n_in,
                              void* d_out, int out_size, void* d_ws, size_t ws_size,
                              hipStream_t stream) {
    const float* x    = (const float*)d_in[0];
    const float* w    = (const float*)d_in[1];
    const float* mk   = (const float*)d_in[2];
    const float* bs   = (const float*)d_in[3];
    float* out        = (float*)d_out;
    unsigned short* pw = (unsigned short*)d_ws;   // [0, 147456)

    pack_w_kernel<<<dim3(NSTEPS), dim3(256), 0, stream>>>(w, mk, pw);

    if (ws_size >= (size_t)XT_OFF + XT_BYTES) {
        unsigned short* xT = (unsigned short*)((char*)d_ws + XT_OFF);
        transpose_x_kernel<<<dim3((PPIX + 255) / 256, NB), dim3(256), 0, stream>>>(x, xT);
        sparse_conv_areg_kernel<<<dim3(448), dim3(256), 0, stream>>>(xT, pw, bs, out);
    } else {
        sparse_conv_fb_kernel<<<dim3(NB * NTILES), dim3(256), 0, stream>>>(x, pw, bs, out);
    }
}

// Round 8
// 115.895 us; speedup vs baseline: 1.7072x; 1.7072x over previous
//
#include <hip/hip_runtime.h>
#include <hip/hip_bf16.h>

#define C_IN    64
#define C_OUT   128
#define HH      112
#define WW      112
#define NB      16
#define KTOT    576      // C_IN * 9
#define NSTEPS  36       // KTOT / 16
#define NPIX    (HH*WW)  // 12544
#define PH      114      // padded spatial dim
#define PPIX    (PH*PH)  // 12996
#define XT_OFF  147456   // bytes: pw occupies [0, 147456)
#define XT_BYTES ((size_t)NB * PPIX * C_IN * 2)
#define A_BYTES 73728    // 36 t * 2 mt * 64 lanes * 16 B
// fallback tiling (round-2 kernel)
#define TY      8
#define TX      16
#define HALO_X  18
#define HALO_P  180
#define TILES_X 7
#define NTILES  98

typedef __bf16 bf16x8 __attribute__((ext_vector_type(8)));
typedef float  f32x16 __attribute__((ext_vector_type(16)));

static __device__ __forceinline__ unsigned short f2bf(float v) {
    unsigned int u = __builtin_bit_cast(unsigned int, v);
    u = u + 0x7fffu + ((u >> 16) & 1u);   // RNE
    return (unsigned short)(u >> 16);
}

// ---------------- pack spW = weight*mask into bf16 MFMA A-fragments ----------------
// pw_frag[t][mt][lane] = 16 B (8 bf16); k_log(t,g,e)=t*16+g*8+e; ij=k_log>>6, c=k_log&63; k_orig=c*9+ij
__global__ __launch_bounds__(256) void pack_w_kernel(
        const float* __restrict__ weight, const float* __restrict__ mask,
        unsigned short* __restrict__ pw) {
    int t  = blockIdx.x;           // 0..35
    int mt = threadIdx.x >> 6;     // 0..3
    int l  = threadIdx.x & 63;
    int g  = l >> 5;
    int m  = mt * 32 + (l & 31);
    unsigned int words[4];
    #pragma unroll
    for (int ew = 0; ew < 4; ++ew) {
        unsigned int w2[2];
        #pragma unroll
        for (int h = 0; h < 2; ++h) {
            int e    = ew * 2 + h;
            int klog = t * 16 + g * 8 + e;
            int ij   = klog >> 6;
            int c    = klog & 63;
            int ko   = c * 9 + ij;
            w2[h] = f2bf(weight[m * KTOT + ko] * mask[m * KTOT + ko]);
        }
        words[ew] = w2[0] | (w2[1] << 16);
    }
    uint4 o4; o4.x = words[0]; o4.y = words[1]; o4.z = words[2]; o4.w = words[3];
    ((uint4*)pw)[(t * 4 + mt) * 64 + l] = o4;
}

// ---------------- pre-pass: x [b][c][h][w] fp32 -> xT [b][hp][wp][c] bf16, zero-padded ----------------
__global__ __launch_bounds__(256) void transpose_x_kernel(
        const float* __restrict__ x, unsigned short* __restrict__ xT) {
    const int b  = blockIdx.y;
    const int pp = blockIdx.x * 256 + threadIdx.x;
    if (pp >= PPIX) return;
    const int hp = pp / PH, wp = pp - hp * PH;
    const int gh = hp - 1, gw = wp - 1;
    const bool valid = (unsigned)gh < (unsigned)HH && (unsigned)gw < (unsigned)WW;
    const float* src = x + (size_t)b * C_IN * (HH * WW) + (gh * WW + gw);
    uint4* dst = (uint4*)(xT + ((size_t)b * PPIX + pp) * C_IN);
    #pragma unroll
    for (int cb = 0; cb < 8; ++cb) {
        unsigned int w4[4];
        #pragma unroll
        for (int h = 0; h < 4; ++h) {
            float v0 = valid ? src[(size_t)(cb * 8 + h * 2    ) * (HH * WW)] : 0.0f;
            float v1 = valid ? src[(size_t)(cb * 8 + h * 2 + 1) * (HH * WW)] : 0.0f;
            w4[h] = (unsigned)f2bf(v0) | ((unsigned)f2bf(v1) << 16);
        }
        uint4 o; o.x = w4[0]; o.y = w4[1]; o.z = w4[2]; o.w = w4[3];
        dst[cb] = o;
    }
}

// ---------------- main conv: A in LDS (once), B direct from global L2, no inner barriers ----------------
// Block (256 thr, 4 waves) = M-half mh (64 c_out) x 256 consecutive output pixels.
// Wave w owns 64 px (2 N-tiles of 32); computes both M-tiles (2M x 2N = 4 MFMA / K-step).
// B fragment = per-lane 16B chunk of an xT pixel record -> global_load_dwordx4, dbuf by tap.
__global__ __launch_bounds__(256, 2) void sparse_conv_bg_kernel(
        const unsigned short* __restrict__ xT, const unsigned short* __restrict__ pw,
        const float* __restrict__ bias, float* __restrict__ out) {
    __shared__ __align__(16) unsigned char As[A_BYTES];   // 73728 B

    // XCD-bijective swizzle: 1568 % 8 == 0; XCD k gets 196 contiguous bids = 2 images
    const int bid = (blockIdx.x & 7) * 196 + (blockIdx.x >> 3);
    const int b   = bid / 98;
    const int rem = bid % 98;
    const int mh  = rem / 49;
    const int p0  = (rem % 49) * 256;
    const int tid = threadIdx.x;
    const int wave = tid >> 6, l = tid & 63;
    const int g = l >> 5, ln = l & 31;

    const char* xTb = (const char*)xT + (size_t)b * PPIX * (C_IN * 2);

    // ---- stage A once: 18 rounds of global_load_lds (73728 B exact, linear) ----
    {
        const char* pwb = (const char*)pw;
        #pragma unroll
        for (int r = 0; r < 18; ++r) {
            int c  = r * 256 + tid;          // c = (t*2+mt)*64 + lane
            int t  = c >> 7;
            int mt = (c >> 6) & 1;
            int ll = c & 63;
            const char* gp = pwb + (size_t)((t * 4 + mh * 2 + mt) * 64 + ll) * 16;
            char* lp = (char*)As + r * 4096 + wave * 1024;   // + lane*16 by HW
            __builtin_amdgcn_global_load_lds(
                (const __attribute__((address_space(1))) void*)gp,
                (__attribute__((address_space(3))) void*)lp, 16, 0, 0);
        }
    }

    // per-lane pixel -> padded record base (taps add di*PH+dj; pad absorbs the -1)
    int rec0[2];
    #pragma unroll
    for (int ntp = 0; ntp < 2; ++ntp) {
        int p = p0 + wave * 64 + ntp * 32 + ln;
        int h = p / WW, w = p - h * WW;
        rec0[ntp] = h * PH + w;
    }

    // bias by accumulator slot
    float bv[2][16];
    #pragma unroll
    for (int mtp = 0; mtp < 2; ++mtp)
        #pragma unroll
        for (int r = 0; r < 16; ++r) {
            int mloc = (r & 3) + 8 * (r >> 2) + 4 * g;
            bv[mtp][r] = bias[mh * 64 + mtp * 32 + mloc];
        }

    f32x16 acc[2][2];
    #pragma unroll
    for (int mtp = 0; mtp < 2; ++mtp)
        #pragma unroll
        for (int ntp = 0; ntp < 2; ++ntp)
            #pragma unroll
            for (int r = 0; r < 16; ++r) acc[mtp][ntp][r] = bv[mtp][r];

    __syncthreads();   // A staged (drains vmcnt once)

    // ---- K loop: 9 taps x 4 channel-steps; B global dbuf by tap, A from LDS ----
    uint4 Bb[2][8];
    {   // prologue: tap 0 (di=0,dj=0)
        #pragma unroll
        for (int ntp = 0; ntp < 2; ++ntp)
            #pragma unroll
            for (int cs = 0; cs < 4; ++cs)
                Bb[0][ntp * 4 + cs] = *(const uint4*)(xTb
                    + (size_t)rec0[ntp] * 128 + (cs * 2 + g) * 16);
    }

    #pragma unroll
    for (int ij = 0; ij < 9; ++ij) {
        if (ij < 8) {
            const int di = (ij + 1) / 3, dj = (ij + 1) - di * 3;
            #pragma unroll
            for (int ntp = 0; ntp < 2; ++ntp)
                #pragma unroll
                for (int cs = 0; cs < 4; ++cs)
                    Bb[(ij + 1) & 1][ntp * 4 + cs] = *(const uint4*)(xTb
                        + (size_t)(rec0[ntp] + di * PH + dj) * 128 + (cs * 2 + g) * 16);
        }
        #pragma unroll
        for (int cs = 0; cs < 4; ++cs) {
            const int t = ij * 4 + cs;
            bf16x8 a0 = __builtin_bit_cast(bf16x8,
                *(const uint4*)(As + ((t * 2 + 0) * 64 + l) * 16));
            bf16x8 a1 = __builtin_bit_cast(bf16x8,
                *(const uint4*)(As + ((t * 2 + 1) * 64 + l) * 16));
            #pragma unroll
            for (int ntp = 0; ntp < 2; ++ntp) {
                bf16x8 bb = __builtin_bit_cast(bf16x8, Bb[ij & 1][ntp * 4 + cs]);
                acc[0][ntp] = __builtin_amdgcn_mfma_f32_32x32x16_bf16(a0, bb, acc[0][ntp], 0, 0, 0);
                acc[1][ntp] = __builtin_amdgcn_mfma_f32_32x32x16_bf16(a1, bb, acc[1][ntp], 0, 0, 0);
            }
        }
    }

    // ---- epilogue: full-line stores. C/D col=lane&31 (pixel), row=(r&3)+8*(r>>2)+4*g ----
    const size_t outb = (size_t)b * C_OUT * NPIX;
    #pragma unroll
    for (int mtp = 0; mtp < 2; ++mtp) {
        #pragma unroll
        for (int r = 0; r < 16; ++r) {
            int mloc = (r & 3) + 8 * (r >> 2) + 4 * g;
            int o = mh * 64 + mtp * 32 + mloc;
            #pragma unroll
            for (int ntp = 0; ntp < 2; ++ntp) {
                int p = p0 + wave * 64 + ntp * 32 + ln;
                out[outb + (size_t)o * NPIX + p] = acc[mtp][ntp][r];
            }
        }
    }
}

// ---------------- fallback (round-2 kernel) if ws too small for xT ----------------
__global__ __launch_bounds__(256, 4) void sparse_conv_fb_kernel(
        const float* __restrict__ x, const unsigned short* __restrict__ pw,
        const float* __restrict__ bias, float* __restrict__ out) {
    __shared__ __align__(16) unsigned short xs[HALO_P * C_IN];

    const int bid = blockIdx.x;
    const int b   = bid / NTILES;
    const int t98 = bid % NTILES;
    const int tyi = t98 / TILES_X;
    const int txi = t98 % TILES_X;
    const int h0  = tyi * TY, w0 = txi * TX;
    const int tid = threadIdx.x;

    const float* xb = x + (size_t)b * C_IN * HH * WW;
    {
        const int p  = tid;
        const bool act = p < HALO_P;
        int yy = p / HALO_X;
        int xx = p - yy * HALO_X;
        int gh = h0 + yy - 1, gw = w0 + xx - 1;
        const bool valid = act && (unsigned)gh < (unsigned)HH && (unsigned)gw < (unsigned)WW;
        const float* bp = xb + (gh * WW + gw);
        float v[C_IN];
        #pragma unroll
        for (int c = 0; c < C_IN; ++c)
            v[c] = valid ? bp[c * (HH * WW)] : 0.0f;
        if (act) {
            char* xc = (char*)xs + p * (C_IN * 2);
            #pragma unroll
            for (int j = 0; j < 8; ++j) {
                bf16x8 bvv;
                #pragma unroll
                for (int e = 0; e < 8; ++e) bvv[e] = (__bf16)v[j * 8 + e];
                *(uint4*)(xc + (((j ^ p) & 7) << 4)) = __builtin_bit_cast(uint4, bvv);
            }
        }
    }
    __syncthreads();

    const int wave = tid >> 6, l = tid & 63;
    const int wm = wave >> 1, wn = wave & 1;
    const int g  = l >> 5,  ln = l & 31;

    int P0[2];
    #pragma unroll
    for (int ntp = 0; ntp < 2; ++ntp) {
        int pt = wn * 64 + ntp * 32 + ln;
        P0[ntp] = (pt >> 4) * HALO_X + (pt & 15);
    }

    f32x16 acc[2][2];
    #pragma unroll
    for (int i = 0; i < 2; ++i)
        #pragma unroll
        for (int jq = 0; jq < 2; ++jq)
            #pragma unroll
            for (int q = 0; q < 16; ++q) acc[i][jq][q] = 0.0f;

    const uint4* __restrict__ pwv = (const uint4*)pw;

    #pragma unroll 1
    for (int ij = 0; ij < 9; ++ij) {
        const int di = ij / 3;
        const int dj = ij - di * 3;
        const int P0a = P0[0] + di * HALO_X + dj;
        const int P1a = P0[1] + di * HALO_X + dj;
        #pragma unroll
        for (int cs = 0; cs < 4; ++cs) {
            const int t = ij * 4 + cs;
            bf16x8 a0 = __builtin_bit_cast(bf16x8, pwv[(t * 4 + wm * 2 + 0) * 64 + l]);
            bf16x8 a1 = __builtin_bit_cast(bf16x8, pwv[(t * 4 + wm * 2 + 1) * 64 + l]);
            const int jb = cs * 2 + g;
            bf16x8 b0 = __builtin_bit_cast(bf16x8,
                *(const uint4*)((const char*)xs + P0a * (C_IN * 2) + (((jb ^ P0a) & 7) << 4)));
            bf16x8 b1 = __builtin_bit_cast(bf16x8,
                *(const uint4*)((const char*)xs + P1a * (C_IN * 2) + (((jb ^ P1a) & 7) << 4)));
            acc[0][0] = __builtin_amdgcn_mfma_f32_32x32x16_bf16(a0, b0, acc[0][0], 0, 0, 0);
            acc[0][1] = __builtin_amdgcn_mfma_f32_32x32x16_bf16(a0, b1, acc[0][1], 0, 0, 0);
            acc[1][0] = __builtin_amdgcn_mfma_f32_32x32x16_bf16(a1, b0, acc[1][0], 0, 0, 0);
            acc[1][1] = __builtin_amdgcn_mfma_f32_32x32x16_bf16(a1, b1, acc[1][1], 0, 0, 0);
        }
    }

    const size_t outb = (size_t)b * C_OUT * HH * WW;
    #pragma unroll
    for (int mtp = 0; mtp < 2; ++mtp) {
        #pragma unroll
        for (int r = 0; r < 16; ++r) {
            int mloc = (r & 3) + 8 * (r >> 2) + 4 * g;
            int o = (wm * 2 + mtp) * 32 + mloc;
            float bvv = bias[o];
            #pragma unroll
            for (int ntp = 0; ntp < 2; ++ntp) {
                int p  = wn * 64 + ntp * 32 + ln;
                int gh = h0 + (p >> 4), gw = w0 + (p & 15);
                out[outb + ((size_t)o * HH + gh) * WW + gw] = acc[mtp][ntp][r] + bvv;
            }
        }
    }
}

extern "C" void kernel_launch(void* const* d_in, const int* in_sizes, int n_in,
                              void* d_out, int out_size, void* d_ws, size_t ws_size,
                              hipStream_t stream) {
    const float* x    = (const float*)d_in[0];
    const float* w    = (const float*)d_in[1];
    const float* mk   = (const float*)d_in[2];
    const float* bs   = (const float*)d_in[3];
    float* out        = (float*)d_out;
    unsigned short* pw = (unsigned short*)d_ws;   // [0, 147456)

    pack_w_kernel<<<dim3(NSTEPS), dim3(256), 0, stream>>>(w, mk, pw);

    if (ws_size >= (size_t)XT_OFF + XT_BYTES) {
        unsigned short* xT = (unsigned short*)((char*)d_ws + XT_OFF);
        transpose_x_kernel<<<dim3((PPIX + 255) / 256, NB), dim3(256), 0, stream>>>(x, xT);
        sparse_conv_bg_kernel<<<dim3(NB * 98), dim3(256), 0, stream>>>(xT, pw, bs, out);
    } else {
        sparse_conv_fb_kernel<<<dim3(NB * NTILES), dim3(256), 0, stream>>>(x, pw, bs, out);
    }
}

// Round 9
// 114.202 us; speedup vs baseline: 1.7325x; 1.0148x over previous
//
#include <hip/hip_runtime.h>
#include <hip/hip_bf16.h>

#define C_IN    64
#define C_OUT   128
#define HH      112
#define WW      112
#define NB      16
#define KTOT    576      // C_IN * 9
#define NSTEPS  36       // KTOT / 16
#define NPIX    (HH*WW)  // 12544
#define PH      114      // padded spatial dim
#define PPIX    (PH*PH)  // 12996
#define XT_OFF  147456   // bytes: pw occupies [0, 147456)
#define XT_BYTES ((size_t)NB * PPIX * C_IN * 2)
// tile geometry (round-3 structure)
#define TY      8
#define TX      16
#define HALO_X  18
#define HALO_P  180      // 10*18
#define TILES_X 7
#define TILES_Y 14
#define NTILES  98

typedef __bf16 bf16x8 __attribute__((ext_vector_type(8)));
typedef float  f32x16 __attribute__((ext_vector_type(16)));

static __device__ __forceinline__ unsigned short f2bf(float v) {
    unsigned int u = __builtin_bit_cast(unsigned int, v);
    u = u + 0x7fffu + ((u >> 16) & 1u);   // RNE
    return (unsigned short)(u >> 16);
}

// ---------------- pack spW = weight*mask into bf16 MFMA A-fragments ----------------
// pw_frag[t][mt][lane] = 16 B (8 bf16); k_log(t,g,e)=t*16+g*8+e; ij=k_log>>6, c=k_log&63; k_orig=c*9+ij
__global__ __launch_bounds__(256) void pack_w_kernel(
        const float* __restrict__ weight, const float* __restrict__ mask,
        unsigned short* __restrict__ pw) {
    int t  = blockIdx.x;           // 0..35
    int mt = threadIdx.x >> 6;     // 0..3
    int l  = threadIdx.x & 63;
    int g  = l >> 5;
    int m  = mt * 32 + (l & 31);
    unsigned int words[4];
    #pragma unroll
    for (int ew = 0; ew < 4; ++ew) {
        unsigned int w2[2];
        #pragma unroll
        for (int h = 0; h < 2; ++h) {
            int e    = ew * 2 + h;
            int klog = t * 16 + g * 8 + e;
            int ij   = klog >> 6;
            int c    = klog & 63;
            int ko   = c * 9 + ij;
            w2[h] = f2bf(weight[m * KTOT + ko] * mask[m * KTOT + ko]);
        }
        words[ew] = w2[0] | (w2[1] << 16);
    }
    uint4 o4; o4.x = words[0]; o4.y = words[1]; o4.z = words[2]; o4.w = words[3];
    ((uint4*)pw)[(t * 4 + mt) * 64 + l] = o4;
}

// ---------------- pre-pass: x [b][c][h][w] fp32 -> xT [b][hp][wp][c] bf16, zero-padded ----------------
__global__ __launch_bounds__(256) void transpose_x_kernel(
        const float* __restrict__ x, unsigned short* __restrict__ xT) {
    const int b  = blockIdx.y;
    const int pp = blockIdx.x * 256 + threadIdx.x;
    if (pp >= PPIX) return;
    const int hp = pp / PH, wp = pp - hp * PH;
    const int gh = hp - 1, gw = wp - 1;
    const bool valid = (unsigned)gh < (unsigned)HH && (unsigned)gw < (unsigned)WW;
    const float* src = x + (size_t)b * C_IN * (HH * WW) + (gh * WW + gw);
    uint4* dst = (uint4*)(xT + ((size_t)b * PPIX + pp) * C_IN);
    #pragma unroll
    for (int cb = 0; cb < 8; ++cb) {
        unsigned int w4[4];
        #pragma unroll
        for (int h = 0; h < 4; ++h) {
            float v0 = valid ? src[(size_t)(cb * 8 + h * 2    ) * (HH * WW)] : 0.0f;
            float v1 = valid ? src[(size_t)(cb * 8 + h * 2 + 1) * (HH * WW)] : 0.0f;
            w4[h] = (unsigned)f2bf(v0) | ((unsigned)f2bf(v1) << 16);
        }
        uint4 o; o.x = w4[0]; o.y = w4[1]; o.z = w4[2]; o.w = w4[3];
        dst[cb] = o;
    }
}

// ---------------- main conv: r3 structure + dual register pipelines ----------------
// Block (256 thr, 4 waves) = all 128 c_out x one 8x16-px tile. Wave (wm,wn) = 2M x 2N.
// A: global->reg pipeline, distance 4 K-steps (Ab[4][2]).
// B: LDS->reg pipeline, distance 2 K-steps (Bb[2][2]); LDS staged once per block.
__global__ __launch_bounds__(256, 2) void sparse_conv_xt_kernel(
        const unsigned short* __restrict__ xT, const unsigned short* __restrict__ pw,
        const float* __restrict__ bias, float* __restrict__ out) {
    __shared__ __align__(16) unsigned short xs[1536 * 8];   // 24576 B (23040 used + slack)

    // XCD-bijective swizzle: 1568 % 8 == 0
    const int bid = (blockIdx.x & 7) * (NB * NTILES / 8) + (blockIdx.x >> 3);
    const int b   = bid / NTILES;
    const int t98 = bid % NTILES;
    const int tyi = t98 / TILES_X;
    const int txi = t98 % TILES_X;
    const int h0  = tyi * TY, w0 = txi * TX;
    const int tid = threadIdx.x;
    const int wave = tid >> 6, l = tid & 63;
    const int wm = wave >> 1, wn = wave & 1;
    const int g  = l >> 5,  ln = l & 31;

    // ---- stage halo: 6 rounds of global_load_lds dwordx4, linear dest, swizzled source ----
    {
        const char* xTb = (const char*)xT + (size_t)b * PPIX * (C_IN * 2);
        #pragma unroll
        for (int r = 0; r < 6; ++r) {
            int chunk = r * 256 + tid;          // 16B chunk = p*8 + slot
            int p = chunk >> 3; if (p > HALO_P - 1) p = HALO_P - 1;   // clamp tail
            int s = chunk & 7;
            int yy = p / HALO_X, xx = p - yy * HALO_X;
            int hp = h0 + yy, wp = w0 + xx;     // padded coords (halo -1 absorbed by pad)
            const char* gp = xTb + (size_t)(hp * PH + wp) * (C_IN * 2) + (((s ^ p) & 7) << 4);
            char* lp = (char*)xs + r * 4096 + wave * 1024;   // + lane*16 done by HW
            __builtin_amdgcn_global_load_lds(
                (const __attribute__((address_space(1))) void*)gp,
                (__attribute__((address_space(3))) void*)lp, 16, 0, 0);
        }
    }

    const uint4* __restrict__ pwv = (const uint4*)pw;

    // ---- A pipeline prologue: t=0..3 issued before barrier (in flight during drain) ----
    uint4 Ab[4][2];
    #pragma unroll
    for (int t = 0; t < 4; ++t) {
        Ab[t][0] = pwv[(t * 4 + wm * 2 + 0) * 64 + l];
        Ab[t][1] = pwv[(t * 4 + wm * 2 + 1) * 64 + l];
    }

    int P0[2];
    #pragma unroll
    for (int ntp = 0; ntp < 2; ++ntp) {
        int pt = wn * 64 + ntp * 32 + ln;   // pixel index in 8x16 tile
        P0[ntp] = (pt >> 4) * HALO_X + (pt & 15);
    }

    f32x16 acc[2][2];
    #pragma unroll
    for (int i = 0; i < 2; ++i)
        #pragma unroll
        for (int jq = 0; jq < 2; ++jq)
            #pragma unroll
            for (int q = 0; q < 16; ++q) acc[i][jq][q] = 0.0f;

    __syncthreads();

    // B LDS read helper (verified swizzle): step t, subtile ntp
    const char* xsb = (const char*)xs;
    #define BLOAD(t, ntp) ({                                                     \
        const int ij_ = (t) >> 2, cs_ = (t) & 3;                                 \
        const int di_ = ij_ / 3, dj_ = ij_ - di_ * 3;                            \
        const int Pa_ = P0[ntp] + di_ * HALO_X + dj_;                            \
        const int jb_ = cs_ * 2 + g;                                             \
        *(const uint4*)(xsb + Pa_ * (C_IN * 2) + (((jb_ ^ Pa_) & 7) << 4)); })

    // ---- B pipeline prologue: t=0,1 ----
    uint4 Bb[2][2];
    #pragma unroll
    for (int t = 0; t < 2; ++t) {
        Bb[t][0] = BLOAD(t, 0);
        Bb[t][1] = BLOAD(t, 1);
    }

    // ---- K loop: fully unrolled, A at distance 4, B at distance 2 (static slots) ----
    #pragma unroll
    for (int t = 0; t < NSTEPS; ++t) {
        bf16x8 a0 = __builtin_bit_cast(bf16x8, Ab[t & 3][0]);
        bf16x8 a1 = __builtin_bit_cast(bf16x8, Ab[t & 3][1]);
        bf16x8 b0 = __builtin_bit_cast(bf16x8, Bb[t & 1][0]);
        bf16x8 b1 = __builtin_bit_cast(bf16x8, Bb[t & 1][1]);
        if (t + 4 < NSTEPS) {
            Ab[t & 3][0] = pwv[((t + 4) * 4 + wm * 2 + 0) * 64 + l];
            Ab[t & 3][1] = pwv[((t + 4) * 4 + wm * 2 + 1) * 64 + l];
        }
        if (t + 2 < NSTEPS) {
            Bb[t & 1][0] = BLOAD(t + 2, 0);
            Bb[t & 1][1] = BLOAD(t + 2, 1);
        }
        acc[0][0] = __builtin_amdgcn_mfma_f32_32x32x16_bf16(a0, b0, acc[0][0], 0, 0, 0);
        acc[0][1] = __builtin_amdgcn_mfma_f32_32x32x16_bf16(a0, b1, acc[0][1], 0, 0, 0);
        acc[1][0] = __builtin_amdgcn_mfma_f32_32x32x16_bf16(a1, b0, acc[1][0], 0, 0, 0);
        acc[1][1] = __builtin_amdgcn_mfma_f32_32x32x16_bf16(a1, b1, acc[1][1], 0, 0, 0);
    }
    #undef BLOAD

    // ---- epilogue: C/D layout col=lane&31 (pixel), row=(r&3)+8*(r>>2)+4*(lane>>5) ----
    const size_t outb = (size_t)b * C_OUT * NPIX;
    #pragma unroll
    for (int mtp = 0; mtp < 2; ++mtp) {
        #pragma unroll
        for (int r = 0; r < 16; ++r) {
            int mloc = (r & 3) + 8 * (r >> 2) + 4 * g;
            int o = (wm * 2 + mtp) * 32 + mloc;
            float bv = bias[o];
            #pragma unroll
            for (int ntp = 0; ntp < 2; ++ntp) {
                int p  = wn * 64 + ntp * 32 + ln;
                int gh = h0 + (p >> 4), gw = w0 + (p & 15);
                out[outb + ((size_t)o * HH + gh) * WW + gw] = acc[mtp][ntp][r] + bv;
            }
        }
    }
}

// ---------------- fallback (round-2 kernel) if ws too small for xT ----------------
__global__ __launch_bounds__(256, 4) void sparse_conv_fb_kernel(
        const float* __restrict__ x, const unsigned short* __restrict__ pw,
        const float* __restrict__ bias, float* __restrict__ out) {
    __shared__ __align__(16) unsigned short xs[HALO_P * C_IN];

    const int bid = blockIdx.x;
    const int b   = bid / NTILES;
    const int t98 = bid % NTILES;
    const int tyi = t98 / TILES_X;
    const int txi = t98 % TILES_X;
    const int h0  = tyi * TY, w0 = txi * TX;
    const int tid = threadIdx.x;

    const float* xb = x + (size_t)b * C_IN * HH * WW;
    {
        const int p  = tid;
        const bool act = p < HALO_P;
        int yy = p / HALO_X;
        int xx = p - yy * HALO_X;
        int gh = h0 + yy - 1, gw = w0 + xx - 1;
        const bool valid = act && (unsigned)gh < (unsigned)HH && (unsigned)gw < (unsigned)WW;
        const float* bp = xb + (gh * WW + gw);
        float v[C_IN];
        #pragma unroll
        for (int c = 0; c < C_IN; ++c)
            v[c] = valid ? bp[c * (HH * WW)] : 0.0f;
        if (act) {
            char* xc = (char*)xs + p * (C_IN * 2);
            #pragma unroll
            for (int j = 0; j < 8; ++j) {
                bf16x8 bvv;
                #pragma unroll
                for (int e = 0; e < 8; ++e) bvv[e] = (__bf16)v[j * 8 + e];
                *(uint4*)(xc + (((j ^ p) & 7) << 4)) = __builtin_bit_cast(uint4, bvv);
            }
        }
    }
    __syncthreads();

    const int wave = tid >> 6, l = tid & 63;
    const int wm = wave >> 1, wn = wave & 1;
    const int g  = l >> 5,  ln = l & 31;

    int P0[2];
    #pragma unroll
    for (int ntp = 0; ntp < 2; ++ntp) {
        int pt = wn * 64 + ntp * 32 + ln;
        P0[ntp] = (pt >> 4) * HALO_X + (pt & 15);
    }

    f32x16 acc[2][2];
    #pragma unroll
    for (int i = 0; i < 2; ++i)
        #pragma unroll
        for (int jq = 0; jq < 2; ++jq)
            #pragma unroll
            for (int q = 0; q < 16; ++q) acc[i][jq][q] = 0.0f;

    const uint4* __restrict__ pwv = (const uint4*)pw;

    #pragma unroll 1
    for (int ij = 0; ij < 9; ++ij) {
        const int di = ij / 3;
        const int dj = ij - di * 3;
        const int P0a = P0[0] + di * HALO_X + dj;
        const int P1a = P0[1] + di * HALO_X + dj;
        #pragma unroll
        for (int cs = 0; cs < 4; ++cs) {
            const int t = ij * 4 + cs;
            bf16x8 a0 = __builtin_bit_cast(bf16x8, pwv[(t * 4 + wm * 2 + 0) * 64 + l]);
            bf16x8 a1 = __builtin_bit_cast(bf16x8, pwv[(t * 4 + wm * 2 + 1) * 64 + l]);
            const int jb = cs * 2 + g;
            bf16x8 b0 = __builtin_bit_cast(bf16x8,
                *(const uint4*)((const char*)xs + P0a * (C_IN * 2) + (((jb ^ P0a) & 7) << 4)));
            bf16x8 b1 = __builtin_bit_cast(bf16x8,
                *(const uint4*)((const char*)xs + P1a * (C_IN * 2) + (((jb ^ P1a) & 7) << 4)));
            acc[0][0] = __builtin_amdgcn_mfma_f32_32x32x16_bf16(a0, b0, acc[0][0], 0, 0, 0);
            acc[0][1] = __builtin_amdgcn_mfma_f32_32x32x16_bf16(a0, b1, acc[0][1], 0, 0, 0);
            acc[1][0] = __builtin_amdgcn_mfma_f32_32x32x16_bf16(a1, b0, acc[1][0], 0, 0, 0);
            acc[1][1] = __builtin_amdgcn_mfma_f32_32x32x16_bf16(a1, b1, acc[1][1], 0, 0, 0);
        }
    }

    const size_t outb = (size_t)b * C_OUT * HH * WW;
    #pragma unroll
    for (int mtp = 0; mtp < 2; ++mtp) {
        #pragma unroll
        for (int r = 0; r < 16; ++r) {
            int mloc = (r & 3) + 8 * (r >> 2) + 4 * g;
            int o = (wm * 2 + mtp) * 32 + mloc;
            float bvv = bias[o];
            #pragma unroll
            for (int ntp = 0; ntp < 2; ++ntp) {
                int p  = wn * 64 + ntp * 32 + ln;
                int gh = h0 + (p >> 4), gw = w0 + (p & 15);
                out[outb + ((size_t)o * HH + gh) * WW + gw] = acc[mtp][ntp][r] + bvv;
            }
        }
    }
}

extern "C" void kernel_launch(void* const* d_in, const int* in_sizes, int n_in,
                              void* d_out, int out_size, void* d_ws, size_t ws_size,
                              hipStream_t stream) {
    const float* x    = (const float*)d_in[0];
    const float* w    = (const float*)d_in[1];
    const float* mk   = (const float*)d_in[2];
    const float* bs   = (const float*)d_in[3];
    float* out        = (float*)d_out;
    unsigned short* pw = (unsigned short*)d_ws;   // [0, 147456)

    pack_w_kernel<<<dim3(NSTEPS), dim3(256), 0, stream>>>(w, mk, pw);

    if (ws_size >= (size_t)XT_OFF + XT_BYTES) {
        unsigned short* xT = (unsigned short*)((char*)d_ws + XT_OFF);
        transpose_x_kernel<<<dim3((PPIX + 255) / 256, NB), dim3(256), 0, stream>>>(x, xT);
        sparse_conv_xt_kernel<<<dim3(NB * NTILES), dim3(256), 0, stream>>>(xT, pw, bs, out);
    } else {
        sparse_conv_fb_kernel<<<dim3(NB * NTILES), dim3(256), 0, stream>>>(x, pw, bs, out);
    }
}